// Round 1
// baseline (2417.700 us; speedup 1.0000x reference)
//
#include <hip/hip_runtime.h>

typedef __attribute__((ext_vector_type(8))) short bf16x8;
typedef __attribute__((ext_vector_type(4))) float f32x4;

#define B_SZ   64
#define IMGSZ  12288            // 3*64*64
#define DENC   26176            // 2*IMGSZ + 1600
#define ENC_H  800
#define DEC_H  1600
#define NZ     100
#define NENC   6400             // 4*ENC_H * 2 (mu gates ++ lv gates)
#define NDEC   6400             // 4*DEC_H
#define KENC   13888            // 12288 (sb) + 1600 (h_dec)
#define KX2    24576            // x duplicated
#define KDEC   1728             // 1600 (h_dec) + 100 (z) + 28 pad
#define GSZ    (B_SZ*NENC)      // 409600 floats per slice
#define NSLICE 8

__device__ __forceinline__ unsigned short f2bf(float f){
  unsigned u = __float_as_uint(f);
  u += 0x7fffu + ((u >> 16) & 1u);
  return (unsigned short)(u >> 16);
}
__device__ __forceinline__ float bf2f(unsigned short h){
  return __uint_as_float(((unsigned)h) << 16);
}
__device__ __forceinline__ float sigf(float x){ return 1.f/(1.f + __expf(-x)); }

// ---------------- conversion / packing kernels ----------------

__global__ __launch_bounds__(256) void k_cvt4(const float* __restrict__ src,
                                              unsigned short* __restrict__ dst,
                                              size_t n4){
  size_t i = (size_t)blockIdx.x*blockDim.x + threadIdx.x;
  size_t stride = (size_t)gridDim.x*blockDim.x;
  const float4* s4 = (const float4*)src;
  ushort4* d4 = (ushort4*)dst;
  for (; i < n4; i += stride){
    float4 v = s4[i];
    ushort4 o;
    o.x = f2bf(v.x); o.y = f2bf(v.y); o.z = f2bf(v.z); o.w = f2bf(v.w);
    d4[i] = o;
  }
}

__global__ __launch_bounds__(256) void k_pack_dec(const float* __restrict__ Whh,
                                                  const float* __restrict__ Wih,
                                                  unsigned short* __restrict__ dst){
  size_t n = (size_t)NDEC*KDEC;
  for (size_t i = (size_t)blockIdx.x*blockDim.x + threadIdx.x; i < n;
       i += (size_t)gridDim.x*blockDim.x){
    int nr = (int)(i / KDEC); int k = (int)(i % KDEC);
    float v = 0.f;
    if (k < DEC_H)          v = Whh[(size_t)nr*DEC_H + k];
    else if (k < DEC_H+NZ)  v = Wih[(size_t)nr*NZ + (k - DEC_H)];
    dst[i] = f2bf(v);
  }
}

__global__ __launch_bounds__(256) void k_x2(const float* __restrict__ x,
                                            unsigned short* __restrict__ dst){
  size_t i = (size_t)blockIdx.x*blockDim.x + threadIdx.x;
  if (i >= (size_t)B_SZ*KX2) return;
  int b = (int)(i / KX2); int k = (int)(i % KX2);
  int ks = (k < IMGSZ) ? k : (k - IMGSZ);
  dst[i] = f2bf(x[(size_t)b*IMGSZ + ks]);
}

// u[b][0:12288] = bf16(-sigmoid(canvas[b][:]))
__global__ __launch_bounds__(256) void k_sb(const float* __restrict__ canvas,
                                            unsigned short* __restrict__ u){
  size_t i = (size_t)blockIdx.x*blockDim.x + threadIdx.x; // over 786432/4
  if (i >= (size_t)B_SZ*IMGSZ/4) return;
  float4 v = ((const float4*)canvas)[i];
  size_t idx = i*4;
  int b = (int)(idx / IMGSZ); int k = (int)(idx % IMGSZ);
  ushort4 o;
  o.x = f2bf(-sigf(v.x)); o.y = f2bf(-sigf(v.y));
  o.z = f2bf(-sigf(v.z)); o.w = f2bf(-sigf(v.w));
  *(ushort4*)(u + (size_t)b*KENC + k) = o;
}

__global__ __launch_bounds__(256) void k_final(const float* __restrict__ canvas,
                                               float* __restrict__ out){
  size_t i = (size_t)blockIdx.x*blockDim.x + threadIdx.x;
  if (i < (size_t)B_SZ*IMGSZ) out[i] = sigf(canvas[i]);
}

__global__ __launch_bounds__(256) void k_g0_reduce(const float* __restrict__ Gpart,
                                                   float* __restrict__ G0){
  size_t i = (size_t)blockIdx.x*blockDim.x + threadIdx.x;
  if (i >= (size_t)GSZ) return;
  float s = 0.f;
#pragma unroll
  for (int p = 0; p < NSLICE; ++p) s += Gpart[(size_t)p*GSZ + i];
  G0[i] = s;
}

// ---------------- MFMA GEMM core ----------------
// Out[row, col] = sum_k A[row, k] * B[n, k]   (B row-major [N][ldb], weights)
// M = 64 fixed (4 MFMA row-frags), wave covers NF*16 output cols.
// MODE 0: Out = acc (write).  MODE 1: Out += acc + bias[col]  (canvas update)
template<int NF, int MODE>
__device__ __forceinline__ void gemm_core(
    const unsigned short* __restrict__ A, int lda,
    const unsigned short* __restrict__ B, int ldb,
    float* __restrict__ Out, int ldo,
    int k0, int k1, int nrow0, int col0,
    const float* __restrict__ bias)
{
  const int lane = threadIdx.x & 63;
  const int wave = threadIdx.x >> 6;
  const int l15 = lane & 15, lg = lane >> 4;

  const unsigned short* pA = A + (size_t)l15*lda + k0 + lg*8;
  const unsigned short* pB[NF];
#pragma unroll
  for (int f = 0; f < NF; ++f)
    pB[f] = B + (size_t)(nrow0 + wave*(NF*16) + f*16 + l15)*ldb + k0 + lg*8;

  f32x4 acc[4][NF];
#pragma unroll
  for (int m = 0; m < 4; ++m)
#pragma unroll
    for (int f = 0; f < NF; ++f)
      acc[m][f] = (f32x4){0.f, 0.f, 0.f, 0.f};

  int k = k0;
  for (; k + 64 <= k1; k += 64){
    bf16x8 b0[NF], b1[NF], a0[4], a1[4];
#pragma unroll
    for (int f = 0; f < NF; ++f){
      b0[f] = *(const bf16x8*)(pB[f]);
      b1[f] = *(const bf16x8*)(pB[f] + 32);
      pB[f] += 64;
    }
#pragma unroll
    for (int m = 0; m < 4; ++m){
      const unsigned short* p = pA + (size_t)m*16*lda;
      a0[m] = *(const bf16x8*)(p);
      a1[m] = *(const bf16x8*)(p + 32);
    }
    pA += 64;
#pragma unroll
    for (int m = 0; m < 4; ++m)
#pragma unroll
      for (int f = 0; f < NF; ++f)
        acc[m][f] = __builtin_amdgcn_mfma_f32_16x16x32_bf16(a0[m], b0[f], acc[m][f], 0, 0, 0);
#pragma unroll
    for (int m = 0; m < 4; ++m)
#pragma unroll
      for (int f = 0; f < NF; ++f)
        acc[m][f] = __builtin_amdgcn_mfma_f32_16x16x32_bf16(a1[m], b1[f], acc[m][f], 0, 0, 0);
  }
  if (k < k1){ // single K=32 tail (e.g. K=800)
    bf16x8 b0[NF], a0[4];
#pragma unroll
    for (int f = 0; f < NF; ++f) b0[f] = *(const bf16x8*)(pB[f]);
#pragma unroll
    for (int m = 0; m < 4; ++m) a0[m] = *(const bf16x8*)(pA + (size_t)m*16*lda);
#pragma unroll
    for (int m = 0; m < 4; ++m)
#pragma unroll
      for (int f = 0; f < NF; ++f)
        acc[m][f] = __builtin_amdgcn_mfma_f32_16x16x32_bf16(a0[m], b0[f], acc[m][f], 0, 0, 0);
  }

#pragma unroll
  for (int m = 0; m < 4; ++m)
#pragma unroll
    for (int f = 0; f < NF; ++f){
      int col = col0 + wave*(NF*16) + f*16 + l15;
#pragma unroll
      for (int j = 0; j < 4; ++j){
        int row = m*16 + lg*4 + j;
        float v = acc[m][f][j];
        float* o = Out + (size_t)row*ldo + col;
        if (MODE == 0) *o = v;
        else           *o += v + bias[col];
      }
    }
}

// ---------------- GEMM wrappers ----------------

// G0 precompute: [64,24576] x2  @ Wenc[:, 0:24576]^T, split-K=8 into Gpart
__global__ __launch_bounds__(256) void k_gemm_g0(const unsigned short* __restrict__ X2,
                                                 const unsigned short* __restrict__ Wenc,
                                                 float* __restrict__ Gpart){
  int k0 = blockIdx.y*3072, k1 = k0 + 3072;
  gemm_core<2,0>(X2, KX2, Wenc, DENC, Gpart + (size_t)blockIdx.y*GSZ, NENC,
                 k0, k1, blockIdx.x*128, blockIdx.x*128, nullptr);
}

// per-step enc: u=[-sb, h_dec] @ Wenc[:, 12288:26176]^T, split-K=8
__global__ __launch_bounds__(256) void k_gemm_enc(const unsigned short* __restrict__ U,
                                                  const unsigned short* __restrict__ Wenc,
                                                  float* __restrict__ Gpart){
  int k0 = blockIdx.y*1792, k1 = k0 + 1792;
  if (k1 > KENC) k1 = KENC;
  gemm_core<2,0>(U, KENC, Wenc + IMGSZ, DENC, Gpart + (size_t)blockIdx.y*GSZ, NENC,
                 k0, k1, blockIdx.x*128, blockIdx.x*128, nullptr);
}

// hh GEMMs (mu cols 0..3199, lv cols 3200..6399) into slice NSLICE
__global__ __launch_bounds__(256) void k_gemm_hh(const unsigned short* __restrict__ hmu,
                                                 const unsigned short* __restrict__ hlv,
                                                 const unsigned short* __restrict__ wm,
                                                 const unsigned short* __restrict__ wl,
                                                 float* __restrict__ OutS){
  int nt = blockIdx.x;
  if (nt < 50) gemm_core<1,0>(hmu, ENC_H, wm, ENC_H, OutS, NENC, 0, ENC_H,
                              nt*64, nt*64, nullptr);
  else         gemm_core<1,0>(hlv, ENC_H, wl, ENC_H, OutS, NENC, 0, ENC_H,
                              (nt-50)*64, 3200 + (nt-50)*64, nullptr);
}

__global__ __launch_bounds__(256) void k_gemm_dec(const unsigned short* __restrict__ U2,
                                                  const unsigned short* __restrict__ Wdec,
                                                  float* __restrict__ Gdec){
  gemm_core<1,0>(U2, KDEC, Wdec, KDEC, Gdec, NDEC, 0, KDEC,
                 blockIdx.x*64, blockIdx.x*64, nullptr);
}

// write GEMM: canvas += h_dec @ W_write^T + b_write
__global__ __launch_bounds__(256) void k_gemm_write(const unsigned short* __restrict__ U2,
                                                    const unsigned short* __restrict__ Wwr,
                                                    float* __restrict__ canvas,
                                                    const float* __restrict__ bwr){
  gemm_core<2,1>(U2, KDEC, Wwr, DEC_H, canvas, IMGSZ, 0, DEC_H,
                 blockIdx.x*128, blockIdx.x*128, bwr);
}

// ---------------- cell / fc kernels ----------------

__global__ __launch_bounds__(256) void k_enc_cell(const float* __restrict__ G0,
                                                  const float* __restrict__ Gpart,
                                                  const float* __restrict__ bmu,
                                                  const float* __restrict__ blv,
                                                  float* __restrict__ cmu,
                                                  float* __restrict__ clv,
                                                  unsigned short* __restrict__ hmu,
                                                  unsigned short* __restrict__ hlv){
  int b = blockIdx.x >> 1, which = blockIdx.x & 1;
  const float* bias = which ? blv : bmu;
  float* C = which ? clv : cmu;
  unsigned short* H = which ? hlv : hmu;
  int base = which * 3200;
  for (int j = threadIdx.x; j < ENC_H; j += blockDim.x){
    float gi = bias[j], gf = bias[ENC_H + j], gg = bias[2*ENC_H + j], go = bias[3*ENC_H + j];
    {
      const float* p = G0 + (size_t)b*NENC + base + j;
      gi += p[0]; gf += p[ENC_H]; gg += p[2*ENC_H]; go += p[3*ENC_H];
    }
    for (int s = 0; s < NSLICE + 1; ++s){
      const float* p = Gpart + (size_t)s*GSZ + (size_t)b*NENC + base + j;
      gi += p[0]; gf += p[ENC_H]; gg += p[2*ENC_H]; go += p[3*ENC_H];
    }
    float cold = C[(size_t)b*ENC_H + j];
    float cn = sigf(gf)*cold + sigf(gi)*tanhf(gg);
    float h  = sigf(go)*tanhf(cn);
    C[(size_t)b*ENC_H + j] = cn;
    H[(size_t)b*ENC_H + j] = f2bf(h);
  }
}

__global__ __launch_bounds__(256) void k_fc_z(const unsigned short* __restrict__ hmu,
                                              const unsigned short* __restrict__ hlv,
                                              const unsigned short* __restrict__ wfcmu,
                                              const unsigned short* __restrict__ wfclv,
                                              const float* __restrict__ bmufc,
                                              const float* __restrict__ blvfc,
                                              const float* __restrict__ noise_t,
                                              float* __restrict__ outMu,
                                              float* __restrict__ outLv,
                                              unsigned short* __restrict__ u2){
  __shared__ float sm[2*NZ];
  int b = blockIdx.x, t = threadIdx.x;
  if (t < 2*NZ){
    bool ismu = t < NZ;
    int j = ismu ? t : t - NZ;
    const unsigned short* h = (ismu ? hmu : hlv) + (size_t)b*ENC_H;
    const unsigned short* w = (ismu ? wfcmu : wfclv) + (size_t)j*ENC_H;
    const ushort4* h4 = (const ushort4*)h;
    const ushort4* w4 = (const ushort4*)w;
    float s = 0.f;
#pragma unroll 4
    for (int k = 0; k < ENC_H/4; ++k){
      ushort4 hv = h4[k], wv = w4[k];
      s += bf2f(hv.x)*bf2f(wv.x) + bf2f(hv.y)*bf2f(wv.y)
         + bf2f(hv.z)*bf2f(wv.z) + bf2f(hv.w)*bf2f(wv.w);
    }
    s += ismu ? bmufc[j] : blvfc[j];
    s = fmaxf(s, 0.f);
    sm[t] = s;
    if (ismu) outMu[(size_t)b*NZ + j] = s;
    else      outLv[(size_t)b*NZ + j] = s;
  }
  __syncthreads();
  if (t < NZ){
    float mu = sm[t], lv = sm[NZ + t];
    float z = noise_t[(size_t)b*NZ + t]*__expf(0.5f*lv) + mu;
    u2[(size_t)b*KDEC + DEC_H + t] = f2bf(z);
  }
}

__global__ __launch_bounds__(256) void k_dec_cell(const float* __restrict__ Gdec,
                                                  const float* __restrict__ bdec,
                                                  float* __restrict__ cdec,
                                                  unsigned short* __restrict__ u,
                                                  unsigned short* __restrict__ u2){
  int b = blockIdx.x;
  for (int j = threadIdx.x; j < DEC_H; j += blockDim.x){
    const float* p = Gdec + (size_t)b*NDEC + j;
    float gi = p[0]        + bdec[j];
    float gf = p[DEC_H]    + bdec[DEC_H + j];
    float gg = p[2*DEC_H]  + bdec[2*DEC_H + j];
    float go = p[3*DEC_H]  + bdec[3*DEC_H + j];
    float cold = cdec[(size_t)b*DEC_H + j];
    float cn = sigf(gf)*cold + sigf(gi)*tanhf(gg);
    float h  = sigf(go)*tanhf(cn);
    cdec[(size_t)b*DEC_H + j] = cn;
    unsigned short hb = f2bf(h);
    u2[(size_t)b*KDEC + j] = hb;                 // dec-gemm A operand (next step) + write-gemm A (this step)
    u[(size_t)b*KENC + IMGSZ + j] = hb;          // enc-gemm h_dec slot (next step)
  }
}

// ---------------- workspace layout ----------------
constexpr size_t SZ_WENC   = (size_t)NENC*DENC*2;        // 335,052,800
constexpr size_t SZ_WHH    = (size_t)3200*ENC_H*2;       // 5,120,000
constexpr size_t SZ_WFC    = (size_t)NZ*ENC_H*2;         // 160,000
constexpr size_t SZ_WDEC   = (size_t)NDEC*KDEC*2;        // 22,118,400
constexpr size_t SZ_WWR    = (size_t)IMGSZ*DEC_H*2;      // 39,321,600
constexpr size_t SZ_X2     = (size_t)B_SZ*KX2*2;         // 3,145,728
constexpr size_t SZ_G0     = (size_t)GSZ*4;              // 1,638,400
constexpr size_t SZ_GPART  = (size_t)(NSLICE+1)*GSZ*4;   // 14,745,600
constexpr size_t SZ_GDEC   = (size_t)B_SZ*NDEC*4;        // 1,638,400
constexpr size_t SZ_CANVAS = (size_t)B_SZ*IMGSZ*4;       // 3,145,728
constexpr size_t SZ_CMU    = (size_t)B_SZ*ENC_H*4;
constexpr size_t SZ_CDEC   = (size_t)B_SZ*DEC_H*4;
constexpr size_t SZ_HMU    = (size_t)B_SZ*ENC_H*2;
constexpr size_t SZ_U      = (size_t)B_SZ*KENC*2;
constexpr size_t SZ_U2     = (size_t)B_SZ*KDEC*2;

constexpr size_t OFF_WENC   = 0;
constexpr size_t OFF_WHHMU  = OFF_WENC   + SZ_WENC;
constexpr size_t OFF_WHHLV  = OFF_WHHMU  + SZ_WHH;
constexpr size_t OFF_WFCMU  = OFF_WHHLV  + SZ_WHH;
constexpr size_t OFF_WFCLV  = OFF_WFCMU  + SZ_WFC;
constexpr size_t OFF_WDEC   = OFF_WFCLV  + SZ_WFC;
constexpr size_t OFF_WWR    = OFF_WDEC   + SZ_WDEC;
constexpr size_t OFF_X2     = OFF_WWR    + SZ_WWR;
constexpr size_t OFF_G0     = OFF_X2     + SZ_X2;
constexpr size_t OFF_GPART  = OFF_G0     + SZ_G0;
constexpr size_t OFF_GDEC   = OFF_GPART  + SZ_GPART;
constexpr size_t OFF_CANVAS = OFF_GDEC   + SZ_GDEC;      // zero-init from here
constexpr size_t OFF_CMU    = OFF_CANVAS + SZ_CANVAS;
constexpr size_t OFF_CLV    = OFF_CMU    + SZ_CMU;
constexpr size_t OFF_CDEC   = OFF_CLV    + SZ_CMU;
constexpr size_t OFF_HMU    = OFF_CDEC   + SZ_CDEC;
constexpr size_t OFF_HLV    = OFF_HMU    + SZ_HMU;
constexpr size_t OFF_U      = OFF_HLV    + SZ_HMU;
constexpr size_t OFF_U2     = OFF_U      + SZ_U;
constexpr size_t OFF_END    = OFF_U2     + SZ_U2;

extern "C" void kernel_launch(void* const* d_in, const int* in_sizes, int n_in,
                              void* d_out, int out_size, void* d_ws, size_t ws_size,
                              hipStream_t stream) {
  const float* x      = (const float*)d_in[0];
  const float* noise  = (const float*)d_in[1];
  const float* Wihmu  = (const float*)d_in[2];
  const float* Whhmu  = (const float*)d_in[3];
  const float* bmu    = (const float*)d_in[4];
  const float* Wihlv  = (const float*)d_in[5];
  const float* Whhlv  = (const float*)d_in[6];
  const float* blv    = (const float*)d_in[7];
  const float* Wmufc  = (const float*)d_in[8];
  const float* bmufc  = (const float*)d_in[9];
  const float* Wlvfc  = (const float*)d_in[10];
  const float* blvfc  = (const float*)d_in[11];
  const float* Wihdec = (const float*)d_in[12];
  const float* Whhdec = (const float*)d_in[13];
  const float* bdec   = (const float*)d_in[14];
  const float* Wwrite = (const float*)d_in[15];
  const float* bwrite = (const float*)d_in[16];
  int T = in_sizes[1] / (B_SZ*NZ);

  if (ws_size < OFF_END) return; // workspace too small -> fail loudly

  char* ws = (char*)d_ws;
  unsigned short* wenc  = (unsigned short*)(ws + OFF_WENC);
  unsigned short* whhmu = (unsigned short*)(ws + OFF_WHHMU);
  unsigned short* whhlv = (unsigned short*)(ws + OFF_WHHLV);
  unsigned short* wfcmu = (unsigned short*)(ws + OFF_WFCMU);
  unsigned short* wfclv = (unsigned short*)(ws + OFF_WFCLV);
  unsigned short* wdec  = (unsigned short*)(ws + OFF_WDEC);
  unsigned short* wwr   = (unsigned short*)(ws + OFF_WWR);
  unsigned short* x2    = (unsigned short*)(ws + OFF_X2);
  float* g0     = (float*)(ws + OFF_G0);
  float* gpart  = (float*)(ws + OFF_GPART);
  float* gdec   = (float*)(ws + OFF_GDEC);
  float* canvas = (float*)(ws + OFF_CANVAS);
  float* cmu    = (float*)(ws + OFF_CMU);
  float* clv    = (float*)(ws + OFF_CLV);
  float* cdec   = (float*)(ws + OFF_CDEC);
  unsigned short* hmu = (unsigned short*)(ws + OFF_HMU);
  unsigned short* hlv = (unsigned short*)(ws + OFF_HLV);
  unsigned short* u   = (unsigned short*)(ws + OFF_U);
  unsigned short* u2  = (unsigned short*)(ws + OFF_U2);

  float* out = (float*)d_out;
  float* outMu = out + (size_t)B_SZ*IMGSZ;                     // 786432
  float* outLv = outMu + (size_t)T*B_SZ*NZ;

  dim3 blk(256);

  // --- one-time: weight conversion f32 -> bf16 ---
  k_cvt4<<<2048, blk, 0, stream>>>(Wihmu, wenc,                      (size_t)3200*DENC/4);
  k_cvt4<<<2048, blk, 0, stream>>>(Wihlv, wenc + (size_t)3200*DENC,  (size_t)3200*DENC/4);
  k_cvt4<<<512,  blk, 0, stream>>>(Whhmu, whhmu, SZ_WHH/2/4);
  k_cvt4<<<512,  blk, 0, stream>>>(Whhlv, whhlv, SZ_WHH/2/4);
  k_cvt4<<<64,   blk, 0, stream>>>(Wmufc, wfcmu, SZ_WFC/2/4);
  k_cvt4<<<64,   blk, 0, stream>>>(Wlvfc, wfclv, SZ_WFC/2/4);
  k_cvt4<<<1024, blk, 0, stream>>>(Wwrite, wwr,  SZ_WWR/2/4);
  k_pack_dec<<<2048, blk, 0, stream>>>(Whhdec, Wihdec, wdec);
  k_x2<<<(B_SZ*KX2)/256, blk, 0, stream>>>(x, x2);

  // zero: canvas + all recurrent state + u + u2 (one contiguous span)
  hipMemsetAsync(ws + OFF_CANVAS, 0, OFF_END - OFF_CANVAS, stream);

  // --- one-time: G0 = x @ (W_A + W_B)^T  via x2=[x,x] over cols 0..24575 ---
  k_gemm_g0<<<dim3(50, NSLICE), blk, 0, stream>>>(x2, wenc, gpart);
  k_g0_reduce<<<GSZ/256, blk, 0, stream>>>(gpart, g0);

  // --- time loop ---
  for (int t = 0; t < T; ++t){
    k_sb<<<(B_SZ*IMGSZ/4)/256, blk, 0, stream>>>(canvas, u);
    k_gemm_enc<<<dim3(50, NSLICE), blk, 0, stream>>>(u, wenc, gpart);
    k_gemm_hh<<<100, blk, 0, stream>>>(hmu, hlv, whhmu, whhlv, gpart + (size_t)NSLICE*GSZ);
    k_enc_cell<<<2*B_SZ, blk, 0, stream>>>(g0, gpart, bmu, blv, cmu, clv, hmu, hlv);
    k_fc_z<<<B_SZ, blk, 0, stream>>>(hmu, hlv, wfcmu, wfclv, bmufc, blvfc,
                                     noise + (size_t)t*B_SZ*NZ,
                                     outMu + (size_t)t*B_SZ*NZ,
                                     outLv + (size_t)t*B_SZ*NZ, u2);
    k_gemm_dec<<<100, blk, 0, stream>>>(u2, wdec, gdec);
    k_dec_cell<<<B_SZ, blk, 0, stream>>>(gdec, bdec, cdec, u, u2);
    k_gemm_write<<<96, blk, 0, stream>>>(u2, wwr, canvas, bwrite);
  }

  k_final<<<(B_SZ*IMGSZ)/256, blk, 0, stream>>>(canvas, out);
}